// Round 2
// baseline (71.646 us; speedup 1.0000x reference)
//
#include <hip/hip_runtime.h>
#include <hip/hip_bf16.h>

#define NENT 8192

// ws[j] packs (float_bits(best_val) << 32) | ~best_row.
// Values are nonnegative floats -> uint bit-order == value order.
// Ties: larger ~row == smaller row == first occurrence (matches jnp.argmax).

__global__ void init_ws_kernel(unsigned long long* __restrict__ ws) {
    int j = blockIdx.x * blockDim.x + threadIdx.x;
    if (j < NENT) ws[j] = 0ull;
}

__global__ __launch_bounds__(256) void proj_max_kernel(
    const float* __restrict__ emb, const float* __restrict__ R,
    const int* __restrict__ is_neg_p, unsigned long long* __restrict__ ws) {
    const int t    = threadIdx.x;
    const int col0 = blockIdx.x * 1024 + t * 4;   // 4 cols per thread, float4
    const int row0 = blockIdx.y * 32;             // 32 rows per chunk
    const int neg  = *is_neg_p;                   // uniform

    __shared__ float se[32];
    if (t < 32) se[t] = emb[row0 + t];
    __syncthreads();

    float best0 = -1.f, best1 = -1.f, best2 = -1.f, best3 = -1.f;
    int   bi0 = 0, bi1 = 0, bi2 = 0, bi3 = 0;

    const float* rp = R + (size_t)row0 * NENT + col0;

#pragma unroll 8
    for (int ii = 0; ii < 32; ++ii) {
        float4 r = *reinterpret_cast<const float4*>(rp);
        rp += NENT;
        if (neg) {  // uniform branch; NEG_SCALE == 1.0
            r.x = 1.f - fminf(1.f, r.x);
            r.y = 1.f - fminf(1.f, r.y);
            r.z = 1.f - fminf(1.f, r.z);
            r.w = 1.f - fminf(1.f, r.w);
        }
        const float e = se[ii];
        const int   i = row0 + ii;
        float p0 = e * r.x, p1 = e * r.y, p2 = e * r.z, p3 = e * r.w;
        if (p0 > best0) { best0 = p0; bi0 = i; }
        if (p1 > best1) { best1 = p1; bi1 = i; }
        if (p2 > best2) { best2 = p2; bi2 = i; }
        if (p3 > best3) { best3 = p3; bi3 = i; }
    }

    unsigned long long pk;
    pk = ((unsigned long long)__float_as_uint(best0) << 32) | (unsigned)(~bi0);
    atomicMax(ws + col0 + 0, pk);
    pk = ((unsigned long long)__float_as_uint(best1) << 32) | (unsigned)(~bi1);
    atomicMax(ws + col0 + 1, pk);
    pk = ((unsigned long long)__float_as_uint(best2) << 32) | (unsigned)(~bi2);
    atomicMax(ws + col0 + 2, pk);
    pk = ((unsigned long long)__float_as_uint(best3) << 32) | (unsigned)(~bi3);
    atomicMax(ws + col0 + 3, pk);
}

__global__ void unpack_kernel(const unsigned long long* __restrict__ ws,
                              float* __restrict__ out) {
    int j = blockIdx.x * blockDim.x + threadIdx.x;
    if (j >= NENT) return;
    unsigned long long p = ws[j];
    float    v   = __uint_as_float((unsigned)(p >> 32));
    unsigned idx = ~(unsigned)(p & 0xFFFFFFFFull);
    out[j]        = v;
    out[NENT + j] = (float)idx;
}

extern "C" void kernel_launch(void* const* d_in, const int* in_sizes, int n_in,
                              void* d_out, int out_size, void* d_ws, size_t ws_size,
                              hipStream_t stream) {
    const float* emb      = (const float*)d_in[0];
    const float* R        = (const float*)d_in[1];
    const int*   is_neg_p = (const int*)d_in[2];
    float* out            = (float*)d_out;
    unsigned long long* ws = (unsigned long long*)d_ws;

    init_ws_kernel<<<NENT / 256, 256, 0, stream>>>(ws);

    dim3 grid(8, 256);  // 8 col-chunks x 256 row-chunks = 2048 blocks
    proj_max_kernel<<<grid, 256, 0, stream>>>(emb, R, is_neg_p, ws);

    unpack_kernel<<<NENT / 256, 256, 0, stream>>>(ws, out);
}

// Round 3
// 53.048 us; speedup vs baseline: 1.3506x; 1.3506x over previous
//
#include <hip/hip_runtime.h>

#define NENT 8192

// pack: (float_bits(val) << 32) | ~row. Values nonneg -> uint order == value
// order; ties -> larger ~row == smaller row == first occurrence (jnp.argmax).
__device__ __forceinline__ unsigned long long pack_vi(float v, int i) {
    return ((unsigned long long)__float_as_uint(v) << 32) | (unsigned)(~i);
}

__device__ __forceinline__ unsigned long long shfl_down_u64(unsigned long long x,
                                                            int off, int width) {
    unsigned hi = (unsigned)(x >> 32), lo = (unsigned)x;
    hi = __shfl_down(hi, off, width);
    lo = __shfl_down(lo, off, width);
    return ((unsigned long long)hi << 32) | lo;
}

// ---------- two-stage path (no atomics) ----------
// pass1: block (x,y) scans rows [32y, 32y+32) for cols [1024x, 1024x+1024),
// writes one packed partial per column: part[y*NENT + col].
__global__ __launch_bounds__(256) void pass1_kernel(
    const float* __restrict__ emb, const float* __restrict__ R,
    const int* __restrict__ is_neg_p, unsigned long long* __restrict__ part) {
    const int t    = threadIdx.x;
    const int col0 = blockIdx.x * 1024 + t * 4;
    const int row0 = blockIdx.y * 32;
    const int neg  = *is_neg_p;  // uniform

    __shared__ float se[32];
    if (t < 32) se[t] = emb[row0 + t];
    __syncthreads();

    float best0 = -1.f, best1 = -1.f, best2 = -1.f, best3 = -1.f;
    int   bi0 = 0, bi1 = 0, bi2 = 0, bi3 = 0;

    const float* rp = R + (size_t)row0 * NENT + col0;
#pragma unroll 8
    for (int ii = 0; ii < 32; ++ii) {
        float4 r = *reinterpret_cast<const float4*>(rp);
        rp += NENT;
        if (neg) {  // NEG_SCALE == 1.0
            r.x = 1.f - fminf(1.f, r.x);
            r.y = 1.f - fminf(1.f, r.y);
            r.z = 1.f - fminf(1.f, r.z);
            r.w = 1.f - fminf(1.f, r.w);
        }
        const float e = se[ii];
        const int   i = row0 + ii;
        float p0 = e * r.x, p1 = e * r.y, p2 = e * r.z, p3 = e * r.w;
        if (p0 > best0) { best0 = p0; bi0 = i; }
        if (p1 > best1) { best1 = p1; bi1 = i; }
        if (p2 > best2) { best2 = p2; bi2 = i; }
        if (p3 > best3) { best3 = p3; bi3 = i; }
    }

    unsigned long long* wp = part + (size_t)blockIdx.y * NENT + col0;
    wp[0] = pack_vi(best0, bi0);
    wp[1] = pack_vi(best1, bi1);
    wp[2] = pack_vi(best2, bi2);
    wp[3] = pack_vi(best3, bi3);
}

// pass2: 8 threads per column reduce the 256 partials; in-wave shfl merge.
__global__ __launch_bounds__(256) void pass2_kernel(
    const unsigned long long* __restrict__ part, float* __restrict__ out) {
    const int t   = threadIdx.x;
    const int col = blockIdx.x * 32 + (t >> 3);
    const int kp  = t & 7;

    unsigned long long best = 0ull;
    const unsigned long long* p = part + (size_t)(kp * 32) * NENT + col;
#pragma unroll 8
    for (int k = 0; k < 32; ++k) {
        unsigned long long v = *p;
        p += NENT;
        best = v > best ? v : best;
    }
    // reduce across the 8 k-partitions (groups of 8 lanes within the wave)
    unsigned long long o;
    o = shfl_down_u64(best, 4, 8); best = o > best ? o : best;
    o = shfl_down_u64(best, 2, 8); best = o > best ? o : best;
    o = shfl_down_u64(best, 1, 8); best = o > best ? o : best;

    if (kp == 0) {
        float    v   = __uint_as_float((unsigned)(best >> 32));
        unsigned idx = ~(unsigned)(best & 0xFFFFFFFFull);
        out[col]        = v;
        out[NENT + col] = (float)idx;
    }
}

// ---------- fallback path (atomics, 64 KiB ws) ----------
__global__ void init_ws_kernel(unsigned long long* __restrict__ ws) {
    int j = blockIdx.x * blockDim.x + threadIdx.x;
    if (j < NENT) ws[j] = 0ull;
}

__global__ __launch_bounds__(256) void proj_atomic_kernel(
    const float* __restrict__ emb, const float* __restrict__ R,
    const int* __restrict__ is_neg_p, unsigned long long* __restrict__ ws) {
    const int t    = threadIdx.x;
    const int col0 = blockIdx.x * 1024 + t * 4;
    const int row0 = blockIdx.y * 128;
    const int neg  = *is_neg_p;

    __shared__ float se[128];
    if (t < 128) se[t] = emb[row0 + t];
    __syncthreads();

    float best0 = -1.f, best1 = -1.f, best2 = -1.f, best3 = -1.f;
    int   bi0 = 0, bi1 = 0, bi2 = 0, bi3 = 0;

    const float* rp = R + (size_t)row0 * NENT + col0;
#pragma unroll 8
    for (int ii = 0; ii < 128; ++ii) {
        float4 r = *reinterpret_cast<const float4*>(rp);
        rp += NENT;
        if (neg) {
            r.x = 1.f - fminf(1.f, r.x);
            r.y = 1.f - fminf(1.f, r.y);
            r.z = 1.f - fminf(1.f, r.z);
            r.w = 1.f - fminf(1.f, r.w);
        }
        const float e = se[ii];
        const int   i = row0 + ii;
        float p0 = e * r.x, p1 = e * r.y, p2 = e * r.z, p3 = e * r.w;
        if (p0 > best0) { best0 = p0; bi0 = i; }
        if (p1 > best1) { best1 = p1; bi1 = i; }
        if (p2 > best2) { best2 = p2; bi2 = i; }
        if (p3 > best3) { best3 = p3; bi3 = i; }
    }
    atomicMax(ws + col0 + 0, pack_vi(best0, bi0));
    atomicMax(ws + col0 + 1, pack_vi(best1, bi1));
    atomicMax(ws + col0 + 2, pack_vi(best2, bi2));
    atomicMax(ws + col0 + 3, pack_vi(best3, bi3));
}

__global__ void unpack_kernel(const unsigned long long* __restrict__ ws,
                              float* __restrict__ out) {
    int j = blockIdx.x * blockDim.x + threadIdx.x;
    if (j >= NENT) return;
    unsigned long long p = ws[j];
    out[j]        = __uint_as_float((unsigned)(p >> 32));
    out[NENT + j] = (float)(~(unsigned)(p & 0xFFFFFFFFull));
}

extern "C" void kernel_launch(void* const* d_in, const int* in_sizes, int n_in,
                              void* d_out, int out_size, void* d_ws, size_t ws_size,
                              hipStream_t stream) {
    const float* emb      = (const float*)d_in[0];
    const float* R        = (const float*)d_in[1];
    const int*   is_neg_p = (const int*)d_in[2];
    float* out            = (float*)d_out;
    unsigned long long* ws = (unsigned long long*)d_ws;

    const size_t need = (size_t)256 * NENT * sizeof(unsigned long long);  // 16 MiB
    if (ws_size >= need) {
        dim3 g1(8, 256);
        pass1_kernel<<<g1, 256, 0, stream>>>(emb, R, is_neg_p, ws);
        pass2_kernel<<<NENT / 32, 256, 0, stream>>>(ws, out);
    } else {
        init_ws_kernel<<<NENT / 256, 256, 0, stream>>>(ws);
        dim3 g1(8, 64);
        proj_atomic_kernel<<<g1, 256, 0, stream>>>(emb, R, is_neg_p, ws);
        unpack_kernel<<<NENT / 256, 256, 0, stream>>>(ws, out);
    }
}